// Round 3
// baseline (445.476 us; speedup 1.0000x reference)
//
#include <hip/hip_runtime.h>
#include <hip/hip_cooperative_groups.h>

#define NELEM (4096 * 4096)
#define KDIM 4096
#define NDIM 4096
#define DOUT 4096
#define EPSQ 1e-8f
#define STRIDE_MEM (2048 * 256)   // streaming kernels: exact grid, compile-time trip counts

typedef __attribute__((ext_vector_type(4))) int i32x4;

typedef __attribute__((address_space(3))) void lds_void;
typedef const __attribute__((address_space(1))) void gbl_void;

__device__ __forceinline__ void load_lds16(const void* g, void* l) {
    __builtin_amdgcn_global_load_lds((gbl_void*)g, (lds_void*)l, 16, 0, 0);
}

__device__ __forceinline__ float wave_max64(float v) {
#pragma unroll
    for (int off = 32; off > 0; off >>= 1)
        v = fmaxf(v, __shfl_down(v, off));
    return v;
}

// ---------------- kernel 1: fused absmax of x, w, b ----------------
__global__ __launch_bounds__(256) void absmax_xwb(
    const float4* __restrict__ x, const float4* __restrict__ w,
    const float* __restrict__ b, unsigned* __restrict__ amax)
{
    float mx = 0.f, mw = 0.f;
    int i = blockIdx.x * 256 + threadIdx.x;
#pragma unroll
    for (int it = 0; it < 8; ++it, i += STRIDE_MEM) {   // 8 * 524288 = NELEM/4 exactly
        float4 a = x[i];
        float4 c = w[i];
        mx = fmaxf(mx, fmaxf(fmaxf(fabsf(a.x), fabsf(a.y)), fmaxf(fabsf(a.z), fabsf(a.w))));
        mw = fmaxf(mw, fmaxf(fmaxf(fabsf(c.x), fabsf(c.y)), fmaxf(fabsf(c.z), fabsf(c.w))));
    }
    float mb = 0.f;
    if (blockIdx.x == 0) {
#pragma unroll
        for (int t = 0; t < DOUT / 256; ++t)
            mb = fmaxf(mb, fabsf(b[t * 256 + threadIdx.x]));
    }

    mx = wave_max64(mx); mw = wave_max64(mw); mb = wave_max64(mb);
    __shared__ float red[3][4];
    const int wave = threadIdx.x >> 6, lane = threadIdx.x & 63;
    if (lane == 0) { red[0][wave] = mx; red[1][wave] = mw; red[2][wave] = mb; }
    __syncthreads();
    if (threadIdx.x == 0) {
        float r0 = fmaxf(fmaxf(red[0][0], red[0][1]), fmaxf(red[0][2], red[0][3]));
        float r1 = fmaxf(fmaxf(red[1][0], red[1][1]), fmaxf(red[1][2], red[1][3]));
        atomicMax(&amax[0], __float_as_uint(r0));
        atomicMax(&amax[1], __float_as_uint(r1));
        if (blockIdx.x == 0) {
            float r2 = fmaxf(fmaxf(red[2][0], red[2][1]), fmaxf(red[2][2], red[2][3]));
            atomicMax(&amax[2], __float_as_uint(r2));
        }
    }
}

// quantize 4 floats to int8 levels, pack into one int32
__device__ __forceinline__ int pack4(float4 a, float s, float qmax) {
    int b0 = (int)fminf(fmaxf(rintf(a.x / s), -qmax), qmax);  // rintf = round-half-even = jnp.round
    int b1 = (int)fminf(fmaxf(rintf(a.y / s), -qmax), qmax);
    int b2 = (int)fminf(fmaxf(rintf(a.z / s), -qmax), qmax);
    int b3 = (int)fminf(fmaxf(rintf(a.w / s), -qmax), qmax);
    return (b0 & 0xff) | ((b1 & 0xff) << 8) | ((b2 & 0xff) << 16) | (b3 << 24);
}

// ---------------- kernel 2: fused quantize (unit-stride: 1 float4 -> 1 int32 per lane-iter) ----
__global__ __launch_bounds__(256) void quant_xwb(
    const float4* __restrict__ x, const float4* __restrict__ w,
    const float* __restrict__ b, const unsigned* __restrict__ amax,
    int* __restrict__ qx, int* __restrict__ qw, float* __restrict__ bq)
{
    const float sx = fmaxf(__uint_as_float(amax[0]) / 127.0f, EPSQ);
    const float sw = fmaxf(__uint_as_float(amax[1]) / 7.0f, EPSQ);
    int i = blockIdx.x * 256 + threadIdx.x;
#pragma unroll
    for (int it = 0; it < 8; ++it, i += STRIDE_MEM) {   // 8 * 524288 = NELEM/4 exactly
        qx[i] = pack4(x[i], sx, 127.f);
        qw[i] = pack4(w[i], sw, 7.f);
    }
    if (blockIdx.x == 0) {
        const float sb = fmaxf(__uint_as_float(amax[2]) / 127.0f, EPSQ);
#pragma unroll
        for (int t = 0; t < DOUT / 256; ++t) {
            int j = t * 256 + threadIdx.x;
            float q = fminf(fmaxf(rintf(b[j] / sb), -127.f), 127.f);
            bq[j] = q * sb;
        }
    }
}

// ---------------- kernel 3a: COOPERATIVE i8 GEMM + fused final fake-quant ----------------
// Phase A: acc = qx@qw^T, o = bq + s*acc, absmax(o) -> amax_out (no store)
// grid.sync()  ->  Phase B: so = amax_out/127; out = clip(round(o/so))*so  (single write)
// LDS exactly 16384 B (red/s_so aliased onto smemA) so runtime occupancy >= 4 blocks/CU
// even under a 64KB-per-CU LDS assumption -> 1024-block co-residency check passes.
__global__ __launch_bounds__(256, 4) void gemm_i8_coop(
    const char* __restrict__ qx, const char* __restrict__ qw,
    const float* __restrict__ bq, const unsigned* __restrict__ amax,
    float* __restrict__ out, unsigned* __restrict__ amax_out)
{
    constexpr int K = KDIM, N = NDIM, BK = 64;
    __shared__ char smemA[128 * BK];   // 8 KB
    __shared__ char smemB[128 * BK];   // 8 KB  (total exactly 16384)

    const int tid = threadIdx.x;
    const int wave = tid >> 6;
    const int lane = tid & 63;
    const int bid = blockIdx.x;        // 1-D grid, 1024 blocks
    const int bm = bid >> 5, bn = bid & 31;

    const int wm = (wave & 1) * 64;
    const int wn = (wave >> 1) * 64;

    i32x4 acc[4][4] = {};

    // T2: linear LDS dest + pre-swizzled global source; read side uses same involution.
    const int srow = wave * 16 + (lane >> 2);
    const int scol = (((lane & 3) ^ ((lane >> 3) & 3)) << 4);
    const char* aP0 = qx + (long)(bm * 128 + srow) * K + scol;
    const char* aP1 = aP0 + 64 * K;
    const char* bP0 = qw + (long)(bn * 128 + srow) * K + scol;
    const char* bP1 = bP0 + 64 * K;
    char* aL0 = smemA + wave * 1024;
    char* aL1 = aL0 + 4096;
    char* bL0 = smemB + wave * 1024;
    char* bL1 = bL0 + 4096;

    const int frow = lane & 15;
    const int fks = (((lane >> 4) ^ ((frow >> 1) & 3)) << 4);

    for (int k0 = 0; k0 < K; k0 += BK) {
        __syncthreads();
        load_lds16(aP0 + k0, aL0);
        load_lds16(aP1 + k0, aL1);
        load_lds16(bP0 + k0, bL0);
        load_lds16(bP1 + k0, bL1);
        __syncthreads();

        i32x4 af[4], bf[4];
#pragma unroll
        for (int i = 0; i < 4; ++i)
            af[i] = *(const i32x4*)(smemA + (wm + i * 16 + frow) * BK + fks);
#pragma unroll
        for (int j = 0; j < 4; ++j)
            bf[j] = *(const i32x4*)(smemB + (wn + j * 16 + frow) * BK + fks);
#pragma unroll
        for (int i = 0; i < 4; ++i)
#pragma unroll
            for (int j = 0; j < 4; ++j)
                acc[i][j] = __builtin_amdgcn_mfma_i32_16x16x64_i8(af[i], bf[j], acc[i][j], 0, 0, 0);
    }

    // ---- Phase A epilogue: absmax only ----
    const float sx = fmaxf(__uint_as_float(amax[0]) / 127.0f, EPSQ);
    const float sw = fmaxf(__uint_as_float(amax[1]) / 7.0f, EPSQ);
    const float s = sx * sw;
    const int col = lane & 15;
    const int rbase = (lane >> 4) * 4;
    float am = 0.f;
    float bqv[4];
#pragma unroll
    for (int j = 0; j < 4; ++j) bqv[j] = bq[bn * 128 + wn + j * 16 + col];

#pragma unroll
    for (int i = 0; i < 4; ++i)
#pragma unroll
        for (int r = 0; r < 4; ++r)
#pragma unroll
            for (int j = 0; j < 4; ++j) {
                float o = fmaf(s, (float)acc[i][j][r], bqv[j]);  // exact: |acc| <= 3.6M < 2^24
                am = fmaxf(am, fabsf(o));
            }
    am = wave_max64(am);

    __syncthreads();                       // all LDS reads of K-loop complete -> smemA reusable
    float* red = (float*)smemA;
    if (lane == 0) red[wave] = am;
    __syncthreads();
    if (tid == 0)
        atomicMax(amax_out, __float_as_uint(fmaxf(fmaxf(red[0], red[1]), fmaxf(red[2], red[3]))));

    cooperative_groups::this_grid().sync();   // amax_out final

    if (tid == 0)
        red[4] = fmaxf(__uint_as_float(atomicMax(amax_out, 0u)) / 127.0f, EPSQ);
    __syncthreads();
    const float so = red[4];

    // ---- Phase B: recompute o from live acc, final fake-quant, single store ----
#pragma unroll
    for (int i = 0; i < 4; ++i)
#pragma unroll
        for (int r = 0; r < 4; ++r) {
            const int m = bm * 128 + wm + i * 16 + rbase + r;
            float* orow = out + (long)m * N + bn * 128 + wn + col;
#pragma unroll
            for (int j = 0; j < 4; ++j) {
                float o = fmaf(s, (float)acc[i][j][r], bqv[j]);
                float q = fminf(fmaxf(rintf(o / so), -127.f), 127.f);
                orow[j * 16] = q * so;
            }
        }
}

// ---------------- kernel 3b: plain i8 GEMM (verified R2) — fallback path ----------------
__global__ __launch_bounds__(256, 2) void gemm_i8(
    const char* __restrict__ qx, const char* __restrict__ qw,
    const float* __restrict__ bq, const unsigned* __restrict__ amax,
    float* __restrict__ out, unsigned* __restrict__ amax_out)
{
    constexpr int K = KDIM, N = NDIM, BK = 64;
    __shared__ char smemA[128 * BK];
    __shared__ char smemB[128 * BK];
    __shared__ float red[4];

    const int tid = threadIdx.x;
    const int wave = tid >> 6;
    const int lane = tid & 63;
    const int bm = blockIdx.y, bn = blockIdx.x;

    const int wm = (wave & 1) * 64;
    const int wn = (wave >> 1) * 64;

    i32x4 acc[4][4] = {};

    const int srow = wave * 16 + (lane >> 2);
    const int scol = (((lane & 3) ^ ((lane >> 3) & 3)) << 4);
    const char* aP0 = qx + (long)(bm * 128 + srow) * K + scol;
    const char* aP1 = aP0 + 64 * K;
    const char* bP0 = qw + (long)(bn * 128 + srow) * K + scol;
    const char* bP1 = bP0 + 64 * K;
    char* aL0 = smemA + wave * 1024;
    char* aL1 = aL0 + 4096;
    char* bL0 = smemB + wave * 1024;
    char* bL1 = bL0 + 4096;

    const int frow = lane & 15;
    const int fks = (((lane >> 4) ^ ((frow >> 1) & 3)) << 4);

    for (int k0 = 0; k0 < K; k0 += BK) {
        __syncthreads();
        load_lds16(aP0 + k0, aL0);
        load_lds16(aP1 + k0, aL1);
        load_lds16(bP0 + k0, bL0);
        load_lds16(bP1 + k0, bL1);
        __syncthreads();

        i32x4 af[4], bf[4];
#pragma unroll
        for (int i = 0; i < 4; ++i)
            af[i] = *(const i32x4*)(smemA + (wm + i * 16 + frow) * BK + fks);
#pragma unroll
        for (int j = 0; j < 4; ++j)
            bf[j] = *(const i32x4*)(smemB + (wn + j * 16 + frow) * BK + fks);
#pragma unroll
        for (int i = 0; i < 4; ++i)
#pragma unroll
            for (int j = 0; j < 4; ++j)
                acc[i][j] = __builtin_amdgcn_mfma_i32_16x16x64_i8(af[i], bf[j], acc[i][j], 0, 0, 0);
    }

    const float sx = fmaxf(__uint_as_float(amax[0]) / 127.0f, EPSQ);
    const float sw = fmaxf(__uint_as_float(amax[1]) / 7.0f, EPSQ);
    const float s = sx * sw;
    const int col = lane & 15;
    const int rbase = (lane >> 4) * 4;
    float am = 0.f;
    float bqv[4];
#pragma unroll
    for (int j = 0; j < 4; ++j) bqv[j] = bq[bn * 128 + wn + j * 16 + col];

#pragma unroll
    for (int i = 0; i < 4; ++i) {
#pragma unroll
        for (int r = 0; r < 4; ++r) {
            const int m = bm * 128 + wm + i * 16 + rbase + r;
            float* orow = out + (long)m * N + bn * 128 + wn + col;
#pragma unroll
            for (int j = 0; j < 4; ++j) {
                float o = fmaf(s, (float)acc[i][j][r], bqv[j]);
                am = fmaxf(am, fabsf(o));
                orow[j * 16] = o;
            }
        }
    }
    am = wave_max64(am);
    if (lane == 0) red[wave] = am;
    __syncthreads();
    if (tid == 0)
        atomicMax(amax_out, __float_as_uint(fmaxf(fmaxf(red[0], red[1]), fmaxf(red[2], red[3]))));
}

// ---------------- kernel 4: in-place final fake-quant (fallback path only) ----------------
__global__ __launch_bounds__(256) void final_quant(
    float4* __restrict__ out, const unsigned* __restrict__ amax)
{
    const float so = fmaxf(__uint_as_float(amax[3]) / 127.0f, EPSQ);
    int i = blockIdx.x * 256 + threadIdx.x;
#pragma unroll
    for (int it = 0; it < 8; ++it, i += STRIDE_MEM) {
        float4 v = out[i];
        v.x = fminf(fmaxf(rintf(v.x / so), -127.f), 127.f) * so;
        v.y = fminf(fmaxf(rintf(v.y / so), -127.f), 127.f) * so;
        v.z = fminf(fmaxf(rintf(v.z / so), -127.f), 127.f) * so;
        v.w = fminf(fmaxf(rintf(v.w / so), -127.f), 127.f) * so;
        out[i] = v;
    }
}

extern "C" void kernel_launch(void* const* d_in, const int* in_sizes, int n_in,
                              void* d_out, int out_size, void* d_ws, size_t ws_size,
                              hipStream_t stream) {
    const float* x = (const float*)d_in[0];   // [4096,4096]
    const float* w = (const float*)d_in[1];   // [4096,4096] (out,in)
    const float* b = (const float*)d_in[2];   // [4096]
    float* out = (float*)d_out;               // [4096,4096] fp32

    char* ws = (char*)d_ws;
    unsigned* amax = (unsigned*)ws;                         // [0]=x,[1]=w,[2]=b,[3]=out
    float* bq = (float*)(ws + 256);                         // 16 KB
    char* qx = (char*)(ws + 32768);                         // 16 MB int8
    char* qw = (char*)(ws + 32768 + (size_t)NELEM);         // 16 MB int8

    hipMemsetAsync(amax, 0, 16, stream);
    hipLaunchKernelGGL(absmax_xwb, dim3(2048), dim3(256), 0, stream,
                       (const float4*)x, (const float4*)w, b, amax);
    hipLaunchKernelGGL(quant_xwb, dim3(2048), dim3(256), 0, stream,
                       (const float4*)x, (const float4*)w, b, amax,
                       (int*)qx, (int*)qw, bq);

    // cooperative fused GEMM+final-quant; on any launch error fall back to verified 2-kernel path
    const char* qxp = (const char*)qx;
    const char* qwp = (const char*)qw;
    const float* bqp = bq;
    const unsigned* amaxp = amax;
    float* outp = out;
    unsigned* amax3 = amax + 3;
    void* kargs[] = {(void*)&qxp, (void*)&qwp, (void*)&bqp, (void*)&amaxp,
                     (void*)&outp, (void*)&amax3};
    hipError_t cerr = hipLaunchCooperativeKernel(
        reinterpret_cast<const void*>(gemm_i8_coop),
        dim3(1024), dim3(256), kargs, 0, stream);
    if (cerr != hipSuccess) {
        (void)hipGetLastError();   // clear sticky error; stream itself is unaffected
        hipLaunchKernelGGL(gemm_i8, dim3(32, 32), dim3(256), 0, stream,
                           (const char*)qx, (const char*)qw, bq, amax, out, amax + 3);
        hipLaunchKernelGGL(final_quant, dim3(2048), dim3(256), 0, stream,
                           (float4*)out, amax);
    }
}

// Round 4
// 280.449 us; speedup vs baseline: 1.5884x; 1.5884x over previous
//
#include <hip/hip_runtime.h>

#define NELEM (4096 * 4096)
#define KDIM 4096
#define NDIM 4096
#define DOUT 4096
#define EPSQ 1e-8f
#define STRIDE_MEM (2048 * 256)   // streaming kernels: exact grid, compile-time trip counts

typedef __attribute__((ext_vector_type(4))) int i32x4;

typedef __attribute__((address_space(3))) void lds_void;
typedef const __attribute__((address_space(1))) void gbl_void;

__device__ __forceinline__ void load_lds16(const void* g, void* l) {
    __builtin_amdgcn_global_load_lds((gbl_void*)g, (lds_void*)l, 16, 0, 0);
}

__device__ __forceinline__ float wave_max64(float v) {
#pragma unroll
    for (int off = 32; off > 0; off >>= 1)
        v = fmaxf(v, __shfl_down(v, off));
    return v;
}

// ---------------- kernel 1: fused absmax of x, w, b ----------------
__global__ __launch_bounds__(256) void absmax_xwb(
    const float4* __restrict__ x, const float4* __restrict__ w,
    const float* __restrict__ b, unsigned* __restrict__ amax)
{
    float mx = 0.f, mw = 0.f;
    int i = blockIdx.x * 256 + threadIdx.x;
#pragma unroll
    for (int it = 0; it < 8; ++it, i += STRIDE_MEM) {   // 8 * 524288 = NELEM/4 exactly
        float4 a = x[i];
        float4 c = w[i];
        mx = fmaxf(mx, fmaxf(fmaxf(fabsf(a.x), fabsf(a.y)), fmaxf(fabsf(a.z), fabsf(a.w))));
        mw = fmaxf(mw, fmaxf(fmaxf(fabsf(c.x), fabsf(c.y)), fmaxf(fabsf(c.z), fabsf(c.w))));
    }
    float mb = 0.f;
    if (blockIdx.x == 0) {
#pragma unroll
        for (int t = 0; t < DOUT / 256; ++t)
            mb = fmaxf(mb, fabsf(b[t * 256 + threadIdx.x]));
    }

    mx = wave_max64(mx); mw = wave_max64(mw); mb = wave_max64(mb);
    __shared__ float red[3][4];
    const int wave = threadIdx.x >> 6, lane = threadIdx.x & 63;
    if (lane == 0) { red[0][wave] = mx; red[1][wave] = mw; red[2][wave] = mb; }
    __syncthreads();
    if (threadIdx.x == 0) {
        float r0 = fmaxf(fmaxf(red[0][0], red[0][1]), fmaxf(red[0][2], red[0][3]));
        float r1 = fmaxf(fmaxf(red[1][0], red[1][1]), fmaxf(red[1][2], red[1][3]));
        atomicMax(&amax[0], __float_as_uint(r0));
        atomicMax(&amax[1], __float_as_uint(r1));
        if (blockIdx.x == 0) {
            float r2 = fmaxf(fmaxf(red[2][0], red[2][1]), fmaxf(red[2][2], red[2][3]));
            atomicMax(&amax[2], __float_as_uint(r2));
        }
    }
}

// quantize 4 floats to int8 levels, pack into one int32
__device__ __forceinline__ int pack4(float4 a, float s, float qmax) {
    int b0 = (int)fminf(fmaxf(rintf(a.x / s), -qmax), qmax);  // rintf = round-half-even = jnp.round
    int b1 = (int)fminf(fmaxf(rintf(a.y / s), -qmax), qmax);
    int b2 = (int)fminf(fmaxf(rintf(a.z / s), -qmax), qmax);
    int b3 = (int)fminf(fmaxf(rintf(a.w / s), -qmax), qmax);
    return (b0 & 0xff) | ((b1 & 0xff) << 8) | ((b2 & 0xff) << 16) | (b3 << 24);
}

// ---------------- kernel 2: fused quantize (unit-stride) ----------------
__global__ __launch_bounds__(256) void quant_xwb(
    const float4* __restrict__ x, const float4* __restrict__ w,
    const float* __restrict__ b, const unsigned* __restrict__ amax,
    int* __restrict__ qx, int* __restrict__ qw, float* __restrict__ bq)
{
    const float sx = fmaxf(__uint_as_float(amax[0]) / 127.0f, EPSQ);
    const float sw = fmaxf(__uint_as_float(amax[1]) / 7.0f, EPSQ);
    int i = blockIdx.x * 256 + threadIdx.x;
#pragma unroll
    for (int it = 0; it < 8; ++it, i += STRIDE_MEM) {
        qx[i] = pack4(x[i], sx, 127.f);
        qw[i] = pack4(w[i], sw, 7.f);
    }
    if (blockIdx.x == 0) {
        const float sb = fmaxf(__uint_as_float(amax[2]) / 127.0f, EPSQ);
#pragma unroll
        for (int t = 0; t < DOUT / 256; ++t) {
            int j = t * 256 + threadIdx.x;
            float q = fminf(fmaxf(rintf(b[j] / sb), -127.f), 127.f);
            bq[j] = q * sb;
        }
    }
}

// ---------------- kernel 3: 256x256-tile phase-split i8 GEMM (T1+T2+T3+T4+T5) ----------------
// 512 threads = 8 waves (2M x 4N). K = 64 slabs of 64B. Ring of 4 slab-buffers per operand
// (LDS 128 KiB). Per phase: counted vmcnt(8) -> raw s_barrier -> prefetch slab s+3 ->
// 12x ds_read_b128 -> setprio(1) 32x MFMA setprio(0). vmcnt never drains to 0 in main loop.
// T2 swizzle identical (byte-for-byte formulas) to the R2-verified zero-conflict kernel.
__global__ __launch_bounds__(512, 2) void gemm_i8_8p(
    const char* __restrict__ qx,   // int8 [4096][4096] (M,K) row-major
    const char* __restrict__ qw,   // int8 [4096][4096] (N,K) row-major
    const float* __restrict__ bq,
    const unsigned* __restrict__ amax,
    float* __restrict__ out,
    unsigned* __restrict__ amax_out)
{
    constexpr int K = KDIM, N = NDIM;
    __shared__ char lds[131072];          // A ring: [4][256][64] @0; B ring: @65536
    char* ldsA = lds;
    char* ldsB = lds + 65536;

    const int tid = threadIdx.x;
    const int wave = tid >> 6, lane = tid & 63;
    // T1 XCD swizzle: 256 blocks, 8 XCDs, chunk 32 -> XCD k owns bm in {2k,2k+1} (A-panel L2 reuse)
    const int swz = (blockIdx.x & 7) * 32 + (blockIdx.x >> 3);
    const int bm = swz >> 4, bn = swz & 15;
    const int wm2 = wave >> 2;            // M-half (0..1), 128 rows
    const int wn4 = wave & 3;             // N-quarter (0..3), 64 cols

    // staging: per issue, 512 threads cover 128 rows x 4 slots(16B). Thread t: row t>>2, slot t&3.
    // Global source slot pre-swizzled (rule 21): sg = (t&3) ^ ((t>>3)&3)  [== R2-verified formula]
    const int sg16 = (((lane & 3) ^ ((lane >> 3) & 3)) << 4);
    const char* aG = qx + (size_t)(bm * 256 + wave * 16 + (lane >> 2)) * K + sg16;
    const char* bG = qw + (size_t)(bn * 256 + wave * 16 + (lane >> 2)) * K + sg16;

    // fragment reads: row = base + frow, k-slot swizzled  [== R2-verified formula, 0 conflicts]
    const int frow = lane & 15;
    const int fks = (((lane >> 4) ^ ((frow >> 1) & 3)) << 4);
    const int aoff = (wm2 * 128 + frow) * 64 + fks;
    const int boff = (wn4 * 64 + frow) * 64 + fks;

    i32x4 acc[8][4] = {};

    // 4 loads/slab/thread: A rows 0-127, A rows 128-255, B rows 0-127, B rows 128-255
#define STAGE8(s) { const int p_ = (s) & 3;                                                  \
    load_lds16(aG + (size_t)(s) * 64,                  ldsA + p_ * 16384 + wave * 1024);     \
    load_lds16(aG + (size_t)128 * K + (size_t)(s) * 64, ldsA + p_ * 16384 + 8192 + wave * 1024); \
    load_lds16(bG + (size_t)(s) * 64,                  ldsB + p_ * 16384 + wave * 1024);     \
    load_lds16(bG + (size_t)128 * K + (size_t)(s) * 64, ldsB + p_ * 16384 + 8192 + wave * 1024); }

#define PHASE8(s, VMN, DO_ST) {                                                              \
    asm volatile("s_waitcnt vmcnt(%0)" :: "n"(VMN) : "memory");                              \
    __builtin_amdgcn_s_barrier();                                                            \
    __builtin_amdgcn_sched_barrier(0);                                                       \
    if (DO_ST) STAGE8((s) + 3);                                                              \
    const char* Ab = ldsA + ((s) & 3) * 16384 + aoff;                                        \
    const char* Bb = ldsB + ((s) & 3) * 16384 + boff;                                        \
    i32x4 af[8], bf[4];                                                                      \
    _Pragma("unroll") for (int mi = 0; mi < 8; ++mi)                                         \
        af[mi] = *(const i32x4*)(Ab + mi * 1024);                                            \
    _Pragma("unroll") for (int ni = 0; ni < 4; ++ni)                                         \
        bf[ni] = *(const i32x4*)(Bb + ni * 1024);                                            \
    __builtin_amdgcn_s_setprio(1);                                                           \
    _Pragma("unroll") for (int mi = 0; mi < 8; ++mi)                                         \
    _Pragma("unroll") for (int ni = 0; ni < 4; ++ni)                                         \
        acc[mi][ni] = __builtin_amdgcn_mfma_i32_16x16x64_i8(af[mi], bf[ni], acc[mi][ni], 0, 0, 0); \
    __builtin_amdgcn_s_setprio(0); }

    // prologue: 3 slabs in flight (12 loads)
    STAGE8(0); STAGE8(1); STAGE8(2);

    // main loop: wait vmcnt(8) (slab s landed, s+1/s+2 in flight), prefetch s+3 -> 12 in flight
    for (int s = 0; s < 61; ++s) PHASE8(s, 8, true);
    // epilogue phases: drain 8 -> 4 -> 0
    PHASE8(61, 8, false);
    PHASE8(62, 4, false);
    PHASE8(63, 0, false);

#undef PHASE8
#undef STAGE8

    // ---- epilogue: o = bq + s*acc; store; absmax -> amax_out ----
    const float sx = fmaxf(__uint_as_float(amax[0]) / 127.0f, EPSQ);
    const float sw = fmaxf(__uint_as_float(amax[1]) / 7.0f, EPSQ);
    const float s = sx * sw;
    const int col = lane & 15;              // C/D: col=lane&15, row=(lane>>4)*4+reg (verified)
    const int rbase = (lane >> 4) * 4;
    float am = 0.f;
    float bqv[4];
#pragma unroll
    for (int ni = 0; ni < 4; ++ni) bqv[ni] = bq[bn * 256 + wn4 * 64 + ni * 16 + col];

#pragma unroll
    for (int mi = 0; mi < 8; ++mi) {
#pragma unroll
        for (int rr = 0; rr < 4; ++rr) {
            const int m = bm * 256 + wm2 * 128 + mi * 16 + rbase + rr;
            float* orow = out + (size_t)m * N + bn * 256 + wn4 * 64 + col;
#pragma unroll
            for (int ni = 0; ni < 4; ++ni) {
                float o = fmaf(s, (float)acc[mi][ni][rr], bqv[ni]);  // exact: |acc| < 2^24
                am = fmaxf(am, fabsf(o));
                orow[ni * 16] = o;
            }
        }
    }
    am = wave_max64(am);
    // red[0..7] at lds[0..31] does not overlap ring slot 3 (phase-63 frags at +49152): safe
    float* red = (float*)lds;
    if (lane == 0) red[wave] = am;
    __syncthreads();
    if (tid == 0) {
        float r = fmaxf(fmaxf(fmaxf(red[0], red[1]), fmaxf(red[2], red[3])),
                        fmaxf(fmaxf(red[4], red[5]), fmaxf(red[6], red[7])));
        atomicMax(amax_out, __float_as_uint(r));
    }
}

// ---------------- kernel 4: in-place final fake-quant of out ----------------
__global__ __launch_bounds__(256) void final_quant(
    float4* __restrict__ out, const unsigned* __restrict__ amax)
{
    const float so = fmaxf(__uint_as_float(amax[3]) / 127.0f, EPSQ);
    int i = blockIdx.x * 256 + threadIdx.x;
#pragma unroll
    for (int it = 0; it < 8; ++it, i += STRIDE_MEM) {
        float4 v = out[i];
        v.x = fminf(fmaxf(rintf(v.x / so), -127.f), 127.f) * so;
        v.y = fminf(fmaxf(rintf(v.y / so), -127.f), 127.f) * so;
        v.z = fminf(fmaxf(rintf(v.z / so), -127.f), 127.f) * so;
        v.w = fminf(fmaxf(rintf(v.w / so), -127.f), 127.f) * so;
        out[i] = v;
    }
}

extern "C" void kernel_launch(void* const* d_in, const int* in_sizes, int n_in,
                              void* d_out, int out_size, void* d_ws, size_t ws_size,
                              hipStream_t stream) {
    const float* x = (const float*)d_in[0];   // [4096,4096]
    const float* w = (const float*)d_in[1];   // [4096,4096] (out,in)
    const float* b = (const float*)d_in[2];   // [4096]
    float* out = (float*)d_out;               // [4096,4096] fp32

    char* ws = (char*)d_ws;
    unsigned* amax = (unsigned*)ws;                         // [0]=x,[1]=w,[2]=b,[3]=out
    float* bq = (float*)(ws + 256);                         // 16 KB
    char* qx = (char*)(ws + 32768);                         // 16 MB int8
    char* qw = (char*)(ws + 32768 + (size_t)NELEM);         // 16 MB int8

    hipMemsetAsync(amax, 0, 16, stream);
    hipLaunchKernelGGL(absmax_xwb, dim3(2048), dim3(256), 0, stream,
                       (const float4*)x, (const float4*)w, b, amax);
    hipLaunchKernelGGL(quant_xwb, dim3(2048), dim3(256), 0, stream,
                       (const float4*)x, (const float4*)w, b, amax,
                       (int*)qx, (int*)qw, bq);
    hipLaunchKernelGGL(gemm_i8_8p, dim3(256), dim3(512), 0, stream,
                       (const char*)qx, (const char*)qw, bq, amax, out, amax + 3);
    hipLaunchKernelGGL(final_quant, dim3(2048), dim3(256), 0, stream,
                       (float4*)out, amax);
}

// Round 5
// 280.273 us; speedup vs baseline: 1.5894x; 1.0006x over previous
//
#include <hip/hip_runtime.h>

#define NELEM (4096 * 4096)
#define KDIM 4096
#define NDIM 4096
#define DOUT 4096
#define EPSQ 1e-8f
#define STRIDE_MEM (2048 * 256)   // streaming kernels: exact grid, compile-time trip counts

typedef __attribute__((ext_vector_type(4))) int i32x4;
typedef __attribute__((ext_vector_type(16))) int i32x16;

typedef __attribute__((address_space(3))) void lds_void;
typedef const __attribute__((address_space(1))) void gbl_void;

__device__ __forceinline__ void load_lds16(const void* g, void* l) {
    __builtin_amdgcn_global_load_lds((gbl_void*)g, (lds_void*)l, 16, 0, 0);
}

__device__ __forceinline__ float wave_max64(float v) {
#pragma unroll
    for (int off = 32; off > 0; off >>= 1)
        v = fmaxf(v, __shfl_down(v, off));
    return v;
}

// amax workspace layout (u32 slots, line-padded to dodge same-address atomic serialization):
//   amax[16*j+0], j=0..7 : x absmax slots      amax[16*j+4], j=0..7 : w absmax slots
//   amax[128] : b absmax                        amax[132] : out absmax

// ---------------- kernel 1: fused absmax of x, w, b (8-slot spread atomics) ----------------
__global__ __launch_bounds__(256) void absmax_xwb(
    const float4* __restrict__ x, const float4* __restrict__ w,
    const float* __restrict__ b, unsigned* __restrict__ amax)
{
    float mx = 0.f, mw = 0.f;
    int i = blockIdx.x * 256 + threadIdx.x;
#pragma unroll
    for (int it = 0; it < 8; ++it, i += STRIDE_MEM) {   // 8 * 524288 = NELEM/4 exactly
        float4 a = x[i];
        float4 c = w[i];
        mx = fmaxf(mx, fmaxf(fmaxf(fabsf(a.x), fabsf(a.y)), fmaxf(fabsf(a.z), fabsf(a.w))));
        mw = fmaxf(mw, fmaxf(fmaxf(fabsf(c.x), fabsf(c.y)), fmaxf(fabsf(c.z), fabsf(c.w))));
    }
    float mb = 0.f;
    if (blockIdx.x == 0) {
#pragma unroll
        for (int t = 0; t < DOUT / 256; ++t)
            mb = fmaxf(mb, fabsf(b[t * 256 + threadIdx.x]));
    }

    mx = wave_max64(mx); mw = wave_max64(mw); mb = wave_max64(mb);
    __shared__ float red[3][4];
    const int wave = threadIdx.x >> 6, lane = threadIdx.x & 63;
    if (lane == 0) { red[0][wave] = mx; red[1][wave] = mw; red[2][wave] = mb; }
    __syncthreads();
    if (threadIdx.x == 0) {
        float r0 = fmaxf(fmaxf(red[0][0], red[0][1]), fmaxf(red[0][2], red[0][3]));
        float r1 = fmaxf(fmaxf(red[1][0], red[1][1]), fmaxf(red[1][2], red[1][3]));
        const int sl = (blockIdx.x & 7) * 16;           // 8 line-padded slots -> 256 atomics/addr
        atomicMax(&amax[sl], __float_as_uint(r0));
        atomicMax(&amax[sl + 4], __float_as_uint(r1));
        if (blockIdx.x == 0) {
            float r2 = fmaxf(fmaxf(red[2][0], red[2][1]), fmaxf(red[2][2], red[2][3]));
            atomicMax(&amax[128], __float_as_uint(r2));
        }
    }
}

// reduce the 8 spread slots (wave-uniform loads, hits L2)
__device__ __forceinline__ void load_scales(const unsigned* __restrict__ amax,
                                            float& sx, float& sw) {
    float sxm = 0.f, swm = 0.f;
#pragma unroll
    for (int j = 0; j < 8; ++j) {
        sxm = fmaxf(sxm, __uint_as_float(amax[j * 16]));
        swm = fmaxf(swm, __uint_as_float(amax[j * 16 + 4]));
    }
    sx = fmaxf(sxm / 127.0f, EPSQ);
    sw = fmaxf(swm / 7.0f, EPSQ);
}

// quantize 4 floats to int8 levels, pack into one int32
__device__ __forceinline__ int pack4(float4 a, float s, float qmax) {
    int b0 = (int)fminf(fmaxf(rintf(a.x / s), -qmax), qmax);  // rintf = round-half-even = jnp.round
    int b1 = (int)fminf(fmaxf(rintf(a.y / s), -qmax), qmax);
    int b2 = (int)fminf(fmaxf(rintf(a.z / s), -qmax), qmax);
    int b3 = (int)fminf(fmaxf(rintf(a.w / s), -qmax), qmax);
    return (b0 & 0xff) | ((b1 & 0xff) << 8) | ((b2 & 0xff) << 16) | (b3 << 24);
}

// ---------------- kernel 2: fused quantize (unit-stride) ----------------
__global__ __launch_bounds__(256) void quant_xwb(
    const float4* __restrict__ x, const float4* __restrict__ w,
    const float* __restrict__ b, const unsigned* __restrict__ amax,
    int* __restrict__ qx, int* __restrict__ qw, float* __restrict__ bq)
{
    float sx, sw;
    load_scales(amax, sx, sw);
    int i = blockIdx.x * 256 + threadIdx.x;
#pragma unroll
    for (int it = 0; it < 8; ++it, i += STRIDE_MEM) {
        qx[i] = pack4(x[i], sx, 127.f);
        qw[i] = pack4(w[i], sw, 7.f);
    }
    if (blockIdx.x == 0) {
        const float sb = fmaxf(__uint_as_float(amax[128]) / 127.0f, EPSQ);
#pragma unroll
        for (int t = 0; t < DOUT / 256; ++t) {
            int j = t * 256 + threadIdx.x;
            float q = fminf(fmaxf(rintf(b[j] / sb), -127.f), 127.f);
            bq[j] = q * sb;
        }
    }
}

// ---------------- kernel 3: 256x256 phase-split i8 GEMM, 32x32x32 MFMA ----------------
// 512 threads = 8 waves (2M x 4N), wave tile 128x64. K = 64 slabs of 64B; ring of 4 (128 KiB).
// Per phase: vmcnt(8) -> s_barrier -> prefetch slab s+3 -> 12x ds_read_b128 ->
// setprio(1) 16x mfma_i32_32x32x32_i8 setprio(0).  vmcnt never 0 in main loop.
// Staging bytes identical to the R2/R4-verified swizzle; read side re-derived for 32-row tiles:
//   slot ∈ {0,1}+2*sub (16B), row = tilebase + (lane&31);  slot' = slot ^ ((row>>1)&3)
//   = slot ^ ((lane>>1)&3)  (tile bases are multiples of 32 -> drop out of (row>>1)&3).
__global__ __launch_bounds__(512, 2) void gemm_i8_8p(
    const char* __restrict__ qx,   // int8 [4096][4096] (M,K) row-major
    const char* __restrict__ qw,   // int8 [4096][4096] (N,K) row-major
    const float* __restrict__ bq,
    const unsigned* __restrict__ amax,
    float* __restrict__ out,
    unsigned* __restrict__ amax_out)
{
    constexpr int K = KDIM, N = NDIM;
    __shared__ char lds[131072];          // A ring: [4][2half][128][64] @0; B ring @65536
    char* ldsA = lds;
    char* ldsB = lds + 65536;

    const int tid = threadIdx.x;
    const int wave = tid >> 6, lane = tid & 63;
    // T1 XCD swizzle: 256 blocks, 8 XCDs, chunk 32 -> XCD k owns bm in {2k,2k+1}
    const int swz = (blockIdx.x & 7) * 32 + (blockIdx.x >> 3);
    const int bm = swz >> 4, bn = swz & 15;
    const int wm2 = wave >> 2;            // M-half (0..1), 128 rows
    const int wn4 = wave & 3;             // N-quarter (0..3), 64 cols

    // staging (verified): thread t -> LDS row wave*16+(lane>>2), slot lane&3;
    // global source slot pre-swizzled: (lane&3) ^ ((lane>>3)&3)
    const int sg16 = (((lane & 3) ^ ((lane >> 3) & 3)) << 4);
    const char* aG = qx + (size_t)(bm * 256 + wave * 16 + (lane >> 2)) * K + sg16;
    const char* bG = qw + (size_t)(bn * 256 + wave * 16 + (lane >> 2)) * K + sg16;

    // fragment reads (32x32x32): lane -> row (lane&31), k-slot (lane>>5) + 2*sub, swizzled
    const int l31 = lane & 31;
    const int fks0 = ((((lane >> 5)) ^ ((lane >> 1) & 3)) << 4);
    const int fks1 = ((((lane >> 5) | 2) ^ ((lane >> 1) & 3)) << 4);
    const int aBase = wm2 * 8192 + l31 * 64;                       // + mi*2048 + fks
    const int bBase = (wn4 >> 1) * 8192 + (wn4 & 1) * 4096 + l31 * 64;  // + ni*2048 + fks

    i32x16 acc[4][2] = {};

#define STAGE8(s) { const int p_ = (s) & 3;                                                  \
    load_lds16(aG + (size_t)(s) * 64,                   ldsA + p_ * 16384 + wave * 1024);    \
    load_lds16(aG + (size_t)128 * K + (size_t)(s) * 64, ldsA + p_ * 16384 + 8192 + wave * 1024); \
    load_lds16(bG + (size_t)(s) * 64,                   ldsB + p_ * 16384 + wave * 1024);    \
    load_lds16(bG + (size_t)128 * K + (size_t)(s) * 64, ldsB + p_ * 16384 + 8192 + wave * 1024); }

#define PHASE8(s, VMN, DO_ST) {                                                              \
    asm volatile("s_waitcnt vmcnt(%0)" :: "n"(VMN) : "memory");                              \
    __builtin_amdgcn_s_barrier();                                                            \
    __builtin_amdgcn_sched_barrier(0);                                                       \
    if (DO_ST) STAGE8((s) + 3);                                                              \
    const char* Ab = ldsA + ((s) & 3) * 16384 + aBase;                                       \
    const char* Bb = ldsB + ((s) & 3) * 16384 + bBase;                                       \
    i32x4 a0[4], a1[4], b0[2], b1[2];                                                        \
    _Pragma("unroll") for (int mi = 0; mi < 4; ++mi) {                                       \
        a0[mi] = *(const i32x4*)(Ab + mi * 2048 + fks0);                                     \
        a1[mi] = *(const i32x4*)(Ab + mi * 2048 + fks1);                                     \
    }                                                                                        \
    _Pragma("unroll") for (int ni = 0; ni < 2; ++ni) {                                       \
        b0[ni] = *(const i32x4*)(Bb + ni * 2048 + fks0);                                     \
        b1[ni] = *(const i32x4*)(Bb + ni * 2048 + fks1);                                     \
    }                                                                                        \
    __builtin_amdgcn_s_setprio(1);                                                           \
    _Pragma("unroll") for (int mi = 0; mi < 4; ++mi)                                         \
    _Pragma("unroll") for (int ni = 0; ni < 2; ++ni)                                         \
        acc[mi][ni] = __builtin_amdgcn_mfma_i32_32x32x32_i8(a0[mi], b0[ni], acc[mi][ni], 0, 0, 0); \
    _Pragma("unroll") for (int mi = 0; mi < 4; ++mi)                                         \
    _Pragma("unroll") for (int ni = 0; ni < 2; ++ni)                                         \
        acc[mi][ni] = __builtin_amdgcn_mfma_i32_32x32x32_i8(a1[mi], b1[ni], acc[mi][ni], 0, 0, 0); \
    __builtin_amdgcn_s_setprio(0); }

    // prologue: 3 slabs in flight (12 loads/wave)
    STAGE8(0); STAGE8(1); STAGE8(2);

    for (int s = 0; s < 61; ++s) PHASE8(s, 8, true);
    PHASE8(61, 8, false);
    PHASE8(62, 4, false);
    PHASE8(63, 0, false);

#undef PHASE8
#undef STAGE8

    // ---- epilogue: o = bq + s*acc; store; absmax -> amax_out ----
    // C/D 32x32: col = lane&31, row = (reg&3) + 8*(reg>>2) + 4*(lane>>5)  [HW-verified]
    float sx, sw;
    load_scales(amax, sx, sw);
    const float s = sx * sw;
    const int col = l31;
    const int r4 = (lane >> 5) * 4;
    float am = 0.f;
    float bqv[2];
#pragma unroll
    for (int ni = 0; ni < 2; ++ni) bqv[ni] = bq[bn * 256 + wn4 * 64 + ni * 32 + col];

#pragma unroll
    for (int mi = 0; mi < 4; ++mi) {
#pragma unroll
        for (int reg = 0; reg < 16; ++reg) {
            const int row = (reg & 3) + 8 * (reg >> 2) + r4;
            const int m = bm * 256 + wm2 * 128 + mi * 32 + row;
            float* orow = out + (size_t)m * N + bn * 256 + wn4 * 64 + col;
#pragma unroll
            for (int ni = 0; ni < 2; ++ni) {
                float o = fmaf(s, (float)acc[mi][ni][reg], bqv[ni]);  // exact: |acc| < 2^24
                am = fmaxf(am, fabsf(o));
                orow[ni * 32] = o;
            }
        }
    }
    am = wave_max64(am);
    float* red = (float*)lds;   // slot-0 region; phase-63 reads were slot 3 -> no collision
    if (lane == 0) red[wave] = am;
    __syncthreads();
    if (tid == 0) {
        float r = fmaxf(fmaxf(fmaxf(red[0], red[1]), fmaxf(red[2], red[3])),
                        fmaxf(fmaxf(red[4], red[5]), fmaxf(red[6], red[7])));
        atomicMax(amax_out, __float_as_uint(r));
    }
}

// ---------------- kernel 4: in-place final fake-quant of out ----------------
__global__ __launch_bounds__(256) void final_quant(
    float4* __restrict__ out, const unsigned* __restrict__ amax_out)
{
    const float so = fmaxf(__uint_as_float(amax_out[0]) / 127.0f, EPSQ);
    int i = blockIdx.x * 256 + threadIdx.x;
#pragma unroll
    for (int it = 0; it < 8; ++it, i += STRIDE_MEM) {
        float4 v = out[i];
        v.x = fminf(fmaxf(rintf(v.x / so), -127.f), 127.f) * so;
        v.y = fminf(fmaxf(rintf(v.y / so), -127.f), 127.f) * so;
        v.z = fminf(fmaxf(rintf(v.z / so), -127.f), 127.f) * so;
        v.w = fminf(fmaxf(rintf(v.w / so), -127.f), 127.f) * so;
        out[i] = v;
    }
}

extern "C" void kernel_launch(void* const* d_in, const int* in_sizes, int n_in,
                              void* d_out, int out_size, void* d_ws, size_t ws_size,
                              hipStream_t stream) {
    const float* x = (const float*)d_in[0];   // [4096,4096]
    const float* w = (const float*)d_in[1];   // [4096,4096] (out,in)
    const float* b = (const float*)d_in[2];   // [4096]
    float* out = (float*)d_out;               // [4096,4096] fp32

    char* ws = (char*)d_ws;
    unsigned* amax = (unsigned*)ws;                         // slot layout above (<= 1 KB)
    float* bq = (float*)(ws + 1024);                        // 16 KB
    char* qx = (char*)(ws + 32768);                         // 16 MB int8
    char* qw = (char*)(ws + 32768 + (size_t)NELEM);         // 16 MB int8

    hipMemsetAsync(amax, 0, 1024, stream);
    hipLaunchKernelGGL(absmax_xwb, dim3(2048), dim3(256), 0, stream,
                       (const float4*)x, (const float4*)w, b, amax);
    hipLaunchKernelGGL(quant_xwb, dim3(2048), dim3(256), 0, stream,
                       (const float4*)x, (const float4*)w, b, amax,
                       (int*)qx, (int*)qw, bq);
    hipLaunchKernelGGL(gemm_i8_8p, dim3(256), dim3(512), 0, stream,
                       (const char*)qx, (const char*)qw, bq, amax, out, amax + 132);
    hipLaunchKernelGGL(final_quant, dim3(2048), dim3(256), 0, stream,
                       (float4*)out, amax + 132);
}

// Round 6
// 278.110 us; speedup vs baseline: 1.6018x; 1.0078x over previous
//
#include <hip/hip_runtime.h>

#define NELEM (4096 * 4096)
#define KDIM 4096
#define NDIM 4096
#define DOUT 4096
#define EPSQ 1e-8f
#define STRIDE_MEM (2048 * 256)   // streaming kernels: exact grid, compile-time trip counts

typedef __attribute__((ext_vector_type(4))) int i32x4;
typedef __attribute__((ext_vector_type(16))) int i32x16;

typedef __attribute__((address_space(3))) void lds_void;
typedef const __attribute__((address_space(1))) void gbl_void;

__device__ __forceinline__ void load_lds16(const void* g, void* l) {
    __builtin_amdgcn_global_load_lds((gbl_void*)g, (lds_void*)l, 16, 0, 0);
}

__device__ __forceinline__ float wave_max64(float v) {
#pragma unroll
    for (int off = 32; off > 0; off >>= 1)
        v = fmaxf(v, __shfl_down(v, off));
    return v;
}

// amax workspace layout (u32 slots, line-padded):
//   amax[16*j+0], j=0..7 : x absmax slots      amax[16*j+4], j=0..7 : w absmax slots
//   amax[128] : b absmax                        amax[132] : out absmax

// ---------------- kernel 1: fused absmax of x, w, b (8-slot spread atomics) ----------------
__global__ __launch_bounds__(256) void absmax_xwb(
    const float4* __restrict__ x, const float4* __restrict__ w,
    const float* __restrict__ b, unsigned* __restrict__ amax)
{
    float mx = 0.f, mw = 0.f;
    int i = blockIdx.x * 256 + threadIdx.x;
#pragma unroll
    for (int it = 0; it < 8; ++it, i += STRIDE_MEM) {   // 8 * 524288 = NELEM/4 exactly
        float4 a = x[i];
        float4 c = w[i];
        mx = fmaxf(mx, fmaxf(fmaxf(fabsf(a.x), fabsf(a.y)), fmaxf(fabsf(a.z), fabsf(a.w))));
        mw = fmaxf(mw, fmaxf(fmaxf(fabsf(c.x), fabsf(c.y)), fmaxf(fabsf(c.z), fabsf(c.w))));
    }
    float mb = 0.f;
    if (blockIdx.x == 0) {
#pragma unroll
        for (int t = 0; t < DOUT / 256; ++t)
            mb = fmaxf(mb, fabsf(b[t * 256 + threadIdx.x]));
    }

    mx = wave_max64(mx); mw = wave_max64(mw); mb = wave_max64(mb);
    __shared__ float red[3][4];
    const int wave = threadIdx.x >> 6, lane = threadIdx.x & 63;
    if (lane == 0) { red[0][wave] = mx; red[1][wave] = mw; red[2][wave] = mb; }
    __syncthreads();
    if (threadIdx.x == 0) {
        float r0 = fmaxf(fmaxf(red[0][0], red[0][1]), fmaxf(red[0][2], red[0][3]));
        float r1 = fmaxf(fmaxf(red[1][0], red[1][1]), fmaxf(red[1][2], red[1][3]));
        const int sl = (blockIdx.x & 7) * 16;           // 8 line-padded slots
        atomicMax(&amax[sl], __float_as_uint(r0));
        atomicMax(&amax[sl + 4], __float_as_uint(r1));
        if (blockIdx.x == 0) {
            float r2 = fmaxf(fmaxf(red[2][0], red[2][1]), fmaxf(red[2][2], red[2][3]));
            atomicMax(&amax[128], __float_as_uint(r2));
        }
    }
}

// reduce the 8 spread slots (wave-uniform loads, hits L2)
__device__ __forceinline__ void load_scales(const unsigned* __restrict__ amax,
                                            float& sx, float& sw) {
    float sxm = 0.f, swm = 0.f;
#pragma unroll
    for (int j = 0; j < 8; ++j) {
        sxm = fmaxf(sxm, __uint_as_float(amax[j * 16]));
        swm = fmaxf(swm, __uint_as_float(amax[j * 16 + 4]));
    }
    sx = fmaxf(sxm / 127.0f, EPSQ);
    sw = fmaxf(swm / 7.0f, EPSQ);
}

// quantize 4 floats to int8 levels, pack into one int32
__device__ __forceinline__ int pack4(float4 a, float s, float qmax) {
    int b0 = (int)fminf(fmaxf(rintf(a.x / s), -qmax), qmax);  // rintf = round-half-even = jnp.round
    int b1 = (int)fminf(fmaxf(rintf(a.y / s), -qmax), qmax);
    int b2 = (int)fminf(fmaxf(rintf(a.z / s), -qmax), qmax);
    int b3 = (int)fminf(fmaxf(rintf(a.w / s), -qmax), qmax);
    return (b0 & 0xff) | ((b1 & 0xff) << 8) | ((b2 & 0xff) << 16) | (b3 << 24);
}

// ---------------- kernel 2: fused quantize (unit-stride) ----------------
__global__ __launch_bounds__(256) void quant_xwb(
    const float4* __restrict__ x, const float4* __restrict__ w,
    const float* __restrict__ b, const unsigned* __restrict__ amax,
    int* __restrict__ qx, int* __restrict__ qw, float* __restrict__ bq)
{
    float sx, sw;
    load_scales(amax, sx, sw);
    int i = blockIdx.x * 256 + threadIdx.x;
#pragma unroll
    for (int it = 0; it < 8; ++it, i += STRIDE_MEM) {
        qx[i] = pack4(x[i], sx, 127.f);
        qw[i] = pack4(w[i], sw, 7.f);
    }
    if (blockIdx.x == 0) {
        const float sb = fmaxf(__uint_as_float(amax[128]) / 127.0f, EPSQ);
#pragma unroll
        for (int t = 0; t < DOUT / 256; ++t) {
            int j = t * 256 + threadIdx.x;
            float q = fminf(fmaxf(rintf(b[j] / sb), -127.f), 127.f);
            bq[j] = q * sb;
        }
    }
}

// ---------------- kernel 3: 256x256 i8 GEMM, 32x32x32 MFMA, MFMA||LDS pipelined ----------------
// 512 threads = 8 waves (2M x 4N). K = 64 slabs of 64B; ring of 4 (128 KiB).
// Per phase (slab s): vmcnt(4) -> barrier -> stage(s+3) -> read 2nd-half frags(s) [6 ds_read]
//   -> 8 MFMA on 1st-half(s) regs (loaded last phase) -> read 1st-half(s+1) [6 ds_read]
//   -> 8 MFMA on 2nd-half(s).  Each read batch issues before an independent MFMA cluster:
// LDS pipe drains under the MFMA pipe (counted lgkm waits by compiler dep-tracking).
// vmcnt BEFORE barrier: per-wave DMA drain + barrier => slab landed for ALL waves (cross-wave
// visibility; a wave reads rows staged by other waves' global_load_lds).
__global__ __launch_bounds__(512, 2) void gemm_i8_8p(
    const char* __restrict__ qx,   // int8 [4096][4096] (M,K) row-major
    const char* __restrict__ qw,   // int8 [4096][4096] (N,K) row-major
    const float* __restrict__ bq,
    const unsigned* __restrict__ amax,
    float* __restrict__ out,
    unsigned* __restrict__ amax_out)
{
    constexpr int K = KDIM, N = NDIM;
    __shared__ char lds[131072];          // A ring: [4][2half][128][64] @0; B ring @65536
    char* ldsA = lds;
    char* ldsB = lds + 65536;

    const int tid = threadIdx.x;
    const int wave = tid >> 6, lane = tid & 63;
    // T1 XCD swizzle: 256 blocks, 8 XCDs, chunk 32
    const int swz = (blockIdx.x & 7) * 32 + (blockIdx.x >> 3);
    const int bm = swz >> 4, bn = swz & 15;
    const int wm2 = wave >> 2;            // M-half (0..1), 128 rows
    const int wn4 = wave & 3;             // N-quarter (0..3), 64 cols

    // staging (harness-verified): thread t -> LDS row wave*16+(lane>>2), slot lane&3;
    // global source slot pre-swizzled: (lane&3) ^ ((lane>>3)&3)
    const int sg16 = (((lane & 3) ^ ((lane >> 3) & 3)) << 4);
    const char* aG = qx + (size_t)(bm * 256 + wave * 16 + (lane >> 2)) * K + sg16;
    const char* bG = qw + (size_t)(bn * 256 + wave * 16 + (lane >> 2)) * K + sg16;

    // fragment reads (harness-verified R5): row lane&31, k-slot (lane>>5)+2*half, swizzled
    const int l31 = lane & 31;
    const int fks0 = ((((lane >> 5)) ^ ((lane >> 1) & 3)) << 4);
    const int fks1 = ((((lane >> 5) | 2) ^ ((lane >> 1) & 3)) << 4);
    const int aBase = wm2 * 8192 + l31 * 64;                            // + mi*2048 + fks
    const int bBase = (wn4 >> 1) * 8192 + (wn4 & 1) * 4096 + l31 * 64;  // + ni*2048 + fks

    i32x16 acc[4][2] = {};
    i32x4 XA[4], XB[2], YA[4], YB[2], A1[4], B1[2];

#define STAGE8(s) { const int p_ = (s) & 3;                                                  \
    load_lds16(aG + (size_t)(s) * 64,                   ldsA + p_ * 16384 + wave * 1024);    \
    load_lds16(aG + (size_t)128 * K + (size_t)(s) * 64, ldsA + p_ * 16384 + 8192 + wave * 1024); \
    load_lds16(bG + (size_t)(s) * 64,                   ldsB + p_ * 16384 + wave * 1024);    \
    load_lds16(bG + (size_t)128 * K + (size_t)(s) * 64, ldsB + p_ * 16384 + 8192 + wave * 1024); }

#define PHASE(s, CA, CB, NA, NB, VMN, DO_ST, DO_NXT) {                                       \
    asm volatile("s_waitcnt vmcnt(%0)" :: "n"(VMN) : "memory");                              \
    __builtin_amdgcn_s_barrier();                                                            \
    __builtin_amdgcn_sched_barrier(0);                                                       \
    if (DO_ST) STAGE8((s) + 3);                                                              \
    { const char* Ab_ = ldsA + ((s) & 3) * 16384 + aBase;                                    \
      const char* Bb_ = ldsB + ((s) & 3) * 16384 + bBase;                                    \
      _Pragma("unroll") for (int mi = 0; mi < 4; ++mi)                                       \
          A1[mi] = *(const i32x4*)(Ab_ + mi * 2048 + fks1);                                  \
      _Pragma("unroll") for (int ni = 0; ni < 2; ++ni)                                       \
          B1[ni] = *(const i32x4*)(Bb_ + ni * 2048 + fks1);                                  \
    }                                                                                        \
    __builtin_amdgcn_sched_barrier(0);                                                       \
    __builtin_amdgcn_s_setprio(1);                                                           \
    _Pragma("unroll") for (int mi = 0; mi < 4; ++mi)                                         \
    _Pragma("unroll") for (int ni = 0; ni < 2; ++ni)                                         \
        acc[mi][ni] = __builtin_amdgcn_mfma_i32_32x32x32_i8(CA[mi], CB[ni], acc[mi][ni], 0, 0, 0); \
    __builtin_amdgcn_s_setprio(0);                                                           \
    __builtin_amdgcn_sched_barrier(0);                                                       \
    if (DO_NXT) {                                                                            \
      const char* An_ = ldsA + (((s) + 1) & 3) * 16384 + aBase;                              \
      const char* Bn_ = ldsB + (((s) + 1) & 3) * 16384 + bBase;                              \
      _Pragma("unroll") for (int mi = 0; mi < 4; ++mi)                                       \
          NA[mi] = *(const i32x4*)(An_ + mi * 2048 + fks0);                                  \
      _Pragma("unroll") for (int ni = 0; ni < 2; ++ni)                                       \
          NB[ni] = *(const i32x4*)(Bn_ + ni * 2048 + fks0);                                  \
    }                                                                                        \
    __builtin_amdgcn_sched_barrier(0);                                                       \
    __builtin_amdgcn_s_setprio(1);                                                           \
    _Pragma("unroll") for (int mi = 0; mi < 4; ++mi)                                         \
    _Pragma("unroll") for (int ni = 0; ni < 2; ++ni)                                         \
        acc[mi][ni] = __builtin_amdgcn_mfma_i32_32x32x32_i8(A1[mi], B1[ni], acc[mi][ni], 0, 0, 0); \
    __builtin_amdgcn_s_setprio(0); }

    // prologue: 3 slabs in flight; read slab0 first-half into X
    STAGE8(0); STAGE8(1); STAGE8(2);
    asm volatile("s_waitcnt vmcnt(8)" ::: "memory");   // slab 0 landed (own loads)
    __builtin_amdgcn_s_barrier();                      // -> landed for all waves
    __builtin_amdgcn_sched_barrier(0);
    {
        const char* Ab_ = ldsA + aBase;
        const char* Bb_ = ldsB + bBase;
#pragma unroll
        for (int mi = 0; mi < 4; ++mi) XA[mi] = *(const i32x4*)(Ab_ + mi * 2048 + fks0);
#pragma unroll
        for (int ni = 0; ni < 2; ++ni) XB[ni] = *(const i32x4*)(Bb_ + ni * 2048 + fks0);
    }

    for (int s = 0; s < 60; s += 2) {
        PHASE(s,     XA, XB, YA, YB, 4, true, true);
        PHASE(s + 1, YA, YB, XA, XB, 4, true, true);
    }
    PHASE(60, XA, XB, YA, YB, 4, true,  true);
    PHASE(61, YA, YB, XA, XB, 4, false, true);
    PHASE(62, XA, XB, YA, YB, 0, false, true);
    PHASE(63, YA, YB, XA, XB, 0, false, false);

#undef PHASE
#undef STAGE8

    // ---- epilogue: o = bq + s*acc; store; absmax -> amax_out ----
    // C/D 32x32: col = lane&31, row = (reg&3) + 8*(reg>>2) + 4*(lane>>5)  [HW-verified]
    float sx, sw;
    load_scales(amax, sx, sw);
    const float s = sx * sw;
    const int col = l31;
    const int r4 = (lane >> 5) * 4;
    float am = 0.f;
    float bqv[2];
#pragma unroll
    for (int ni = 0; ni < 2; ++ni) bqv[ni] = bq[bn * 256 + wn4 * 64 + ni * 32 + col];

#pragma unroll
    for (int mi = 0; mi < 4; ++mi) {
#pragma unroll
        for (int reg = 0; reg < 16; ++reg) {
            const int row = (reg & 3) + 8 * (reg >> 2) + r4;
            const int m = bm * 256 + wm2 * 128 + mi * 32 + row;
            float* orow = out + (size_t)m * N + bn * 256 + wn4 * 64 + col;
#pragma unroll
            for (int ni = 0; ni < 2; ++ni) {
                float o = fmaf(s, (float)acc[mi][ni][reg], bqv[ni]);  // exact: |acc| < 2^24
                am = fmaxf(am, fabsf(o));
                orow[ni * 32] = o;
            }
        }
    }
    am = wave_max64(am);
    float* red = (float*)lds;   // slot-0 bytes; phase-63 reads were slot 3 -> no collision
    if (lane == 0) red[wave] = am;
    __syncthreads();
    if (tid == 0) {
        float r = fmaxf(fmaxf(fmaxf(red[0], red[1]), fmaxf(red[2], red[3])),
                        fmaxf(fmaxf(red[4], red[5]), fmaxf(red[6], red[7])));
        atomicMax(amax_out, __float_as_uint(r));
    }
}

// ---------------- kernel 4: in-place final fake-quant of out ----------------
__global__ __launch_bounds__(256) void final_quant(
    float4* __restrict__ out, const unsigned* __restrict__ amax_out)
{
    const float so = fmaxf(__uint_as_float(amax_out[0]) / 127.0f, EPSQ);
    int i = blockIdx.x * 256 + threadIdx.x;
#pragma unroll
    for (int it = 0; it < 8; ++it, i += STRIDE_MEM) {
        float4 v = out[i];
        v.x = fminf(fmaxf(rintf(v.x / so), -127.f), 127.f) * so;
        v.y = fminf(fmaxf(rintf(v.y / so), -127.f), 127.f) * so;
        v.z = fminf(fmaxf(rintf(v.z / so), -127.f), 127.f) * so;
        v.w = fminf(fmaxf(rintf(v.w / so), -127.f), 127.f) * so;
        out[i] = v;
    }
}

extern "C" void kernel_launch(void* const* d_in, const int* in_sizes, int n_in,
                              void* d_out, int out_size, void* d_ws, size_t ws_size,
                              hipStream_t stream) {
    const float* x = (const float*)d_in[0];   // [4096,4096]
    const float* w = (const float*)d_in[1];   // [4096,4096] (out,in)
    const float* b = (const float*)d_in[2];   // [4096]
    float* out = (float*)d_out;               // [4096,4096] fp32

    char* ws = (char*)d_ws;
    unsigned* amax = (unsigned*)ws;                         // slot layout above (<= 1 KB)
    float* bq = (float*)(ws + 1024);                        // 16 KB
    char* qx = (char*)(ws + 32768);                         // 16 MB int8
    char* qw = (char*)(ws + 32768 + (size_t)NELEM);         // 16 MB int8

    hipMemsetAsync(amax, 0, 1024, stream);
    hipLaunchKernelGGL(absmax_xwb, dim3(2048), dim3(256), 0, stream,
                       (const float4*)x, (const float4*)w, b, amax);
    hipLaunchKernelGGL(quant_xwb, dim3(2048), dim3(256), 0, stream,
                       (const float4*)x, (const float4*)w, b, amax,
                       (int*)qx, (int*)qw, bq);
    hipLaunchKernelGGL(gemm_i8_8p, dim3(256), dim3(512), 0, stream,
                       (const char*)qx, (const char*)qw, bq, amax, out, amax + 132);
    hipLaunchKernelGGL(final_quant, dim3(2048), dim3(256), 0, stream,
                       (float4*)out, amax + 132);
}